// Round 1
// 1065.596 us; speedup vs baseline: 1.0258x; 1.0258x over previous
//
#include <hip/hip_runtime.h>

typedef float v4f __attribute__((ext_vector_type(4)));

// Problem constants (from reference)
constexpr int B = 256;        // batch
constexpr int T = 64;         // trees
constexpr int C = 1000;       // mask columns (idx domain)
constexpr int F = 16080;      // output feature width
constexpr int K = 200;        // top-k
constexpr int F4 = F / 4;     // 4020 float4 per row
constexpr int C4 = C / 4;     // 250 float4 with possible nonzeros
constexpr unsigned ND = (unsigned)B * T * C4;  // 4,096,000 dense (nonzero-region) quads

// Kernel 1: one block per tree. Find top-200 of the mask row via bitonic sort
// of packed keys in LDS, scatter sigmoid values into the (pre-zeroed) attn row.
// Key = (monotone(float_bits) << 32) | ~index  -> descending sort gives
// values descending, ties broken by lower index (matches lax.top_k).
// NOTE: attention row zeroing is now handled by the bulk hipMemsetAsync.
__global__ __launch_bounds__(256) void topk_scatter_kernel(
    const float* __restrict__ mask, float* __restrict__ attn) {
  const int t = blockIdx.x;
  const int tid = threadIdx.x;
  __shared__ unsigned long long keys[1024];

  const float* row = mask + (size_t)t * C;

  // load + pack keys (pad to 1024 with key=0, sorts last in descending order)
  for (int i = tid; i < 1024; i += 256) {
    if (i < C) {
      unsigned ub = __float_as_uint(row[i]);
      unsigned mono = (ub & 0x80000000u) ? ~ub : (ub | 0x80000000u);
      keys[i] = ((unsigned long long)mono << 32) | (unsigned)(~i);
    } else {
      keys[i] = 0ull;
    }
  }
  __syncthreads();

  // bitonic sort, descending
  for (int k = 2; k <= 1024; k <<= 1) {
    for (int j = k >> 1; j > 0; j >>= 1) {
      for (int ii = tid; ii < 1024; ii += 256) {
        int l = ii ^ j;
        if (l > ii) {
          unsigned long long a = keys[ii];
          unsigned long long b2 = keys[l];
          bool sw = ((ii & k) == 0) ? (a < b2) : (a > b2);
          if (sw) { keys[ii] = b2; keys[l] = a; }
        }
      }
      __syncthreads();
    }
  }

  // scatter top-200: attn[t, idx] = sigmoid(value)
  if (tid < K) {
    unsigned long long key = keys[tid];
    unsigned idx = ~(unsigned)(key & 0xFFFFFFFFull);
    unsigned mono = (unsigned)(key >> 32);
    unsigned bits = (mono & 0x80000000u) ? (mono ^ 0x80000000u) : ~mono;
    float v = __uint_as_float(bits);
    float s = 1.0f / (1.0f + expf(-v));
    attn[(size_t)t * F + idx] = s;
  }
}

// Kernel 2: write ONLY the nonzero region — cols [0,1000) of every (b,t) row.
// 65.5 MB of stores instead of sweeping the whole 1.05 GB with a branch;
// the 986 MB zero tail is produced by hipMemsetAsync (rocclr fill, ~6.1 TB/s
// measured on this very buffer). Reads are L2-resident (x live set 1 MB,
// attn 256 KB).
__global__ __launch_bounds__(256) void dense_kernel(
    const float* __restrict__ x, const float* __restrict__ attn,
    float* __restrict__ out) {
  const v4f* __restrict__ x4 = (const v4f*)x;
  const v4f* __restrict__ a4 = (const v4f*)attn;
  v4f* __restrict__ o4 = (v4f*)out;

  const unsigned stride = gridDim.x * 256u;
  for (unsigned j = blockIdx.x * 256u + threadIdx.x; j < ND; j += stride) {
    unsigned row = j / (unsigned)C4;        // compiler magic-mul
    unsigned c = j - row * (unsigned)C4;    // quad col in [0,250)
    unsigned b = row >> 6;
    unsigned t = row & 63u;
    o4[(size_t)row * F4 + c] = x4[b * (unsigned)F4 + c] * a4[t * (unsigned)F4 + c];
  }
}

extern "C" void kernel_launch(void* const* d_in, const int* in_sizes, int n_in,
                              void* d_out, int out_size, void* d_ws, size_t ws_size,
                              hipStream_t stream) {
  const float* x = (const float*)d_in[0];          // (256,120,134) -> (256,16080)
  const float* mask = (const float*)d_in[1];       // (64,1000)
  float* out = (float*)d_out;                      // return_value (256,64,16080)
  float* attn = out + (size_t)B * T * F;           // attention (64,16080), 2nd output

  // 1) bulk-zero both outputs with the runtime fill kernel (~6.1 TB/s measured)
  const size_t total_bytes = ((size_t)B * T + (size_t)T) * (size_t)F * sizeof(float);
  hipMemsetAsync(d_out, 0, total_bytes, stream);

  // 2) top-k + sigmoid scatter into attention rows (depends on memset; same stream)
  topk_scatter_kernel<<<T, 256, 0, stream>>>(mask, attn);

  // 3) dense nonzero region: 4,096,000 float4s, ~8 per thread
  dense_kernel<<<2048, 256, 0, stream>>>(x, attn, out);
}